// Round 1
// baseline (528.815 us; speedup 1.0000x reference)
//
#include <hip/hip_runtime.h>
#include <cfloat>

#define N_TOK 8192
#define DIM 512
#define KCODES 1024
#define LEVELS 3

#define TM 32
#define DK 32
#define KC 512
#define THREADS 512

// d_out float offsets
#define OUT_CODES (N_TOK*DIM)                       // 4194304
#define OUT_COMMIT (OUT_CODES + N_TOK*LEVELS)       // +24576
#define OUT_USAGE (OUT_COMMIT + 1)

// ws float offsets
#define WS_C2 0
#define WS_PROBS (LEVELS*KCODES)
#define WS_COMMIT (2*LEVELS*KCODES)
#define NBLK_B 2048
#define WS_TOTAL_BYTES ((2*LEVELS*KCODES + LEVELS*NBLK_B)*4)

// ---------------------------------------------------------------- c2 = ||cb_k||^2
__global__ void c2_kernel(const float* __restrict__ cb, float* __restrict__ ws) {
  int row = blockIdx.x * 4 + (threadIdx.x >> 6);   // 0..3071 (levels*K)
  int lane = threadIdx.x & 63;
  const float* p = cb + (size_t)row * DIM;
  float s = 0.f;
  #pragma unroll
  for (int j = 0; j < DIM/64; ++j) { float v = p[lane + 64*j]; s = fmaf(v, v, s); }
  #pragma unroll
  for (int m = 32; m; m >>= 1) s += __shfl_xor(s, m, 64);
  if (lane == 0) ws[WS_C2 + row] = s;
}

// ---------------------------------------------------------------- main per-level kernel
// block: 512 threads = 8 waves; each wave owns 4 tokens, each lane 16 codes (c = lane + 64*jj)
__launch_bounds__(THREADS, 2)
__global__ void rvq_level_kernel(const float* __restrict__ x,
                                 const float* __restrict__ qsum,
                                 const float* __restrict__ cb,     // this level [K][D]
                                 const float* __restrict__ c2,     // this level [K]
                                 float* __restrict__ probs_g,      // this level [K]
                                 float* __restrict__ codes_out,    // d_out + OUT_CODES
                                 int level)
{
  extern __shared__ float smem[];
  float* cb_tile   = smem;                      // KC*DK = 16384 floats (64KB), XOR-swizzled
  float* r_tile    = smem + KC*DK;              // TM*DK = 1024 floats (4KB)
  float* probs_lds = smem + KC*DK + TM*DK;      // KCODES floats (4KB)

  const int tid = threadIdx.x;
  const int w = tid >> 6;
  const int l = tid & 63;
  const int tok0 = blockIdx.x * TM;

  for (int i = tid; i < KCODES; i += THREADS) probs_lds[i] = 0.f;

  // ---- x2 per token (4 tokens per wave), r = x - qsum
  float x2[4];
  #pragma unroll
  for (int mi = 0; mi < 4; ++mi) {
    int n = tok0 + w*4 + mi;
    const float4* xp = (const float4*)(x + (size_t)n*DIM);
    const float4* qp = (const float4*)(qsum + (size_t)n*DIM);
    float s = 0.f;
    #pragma unroll
    for (int j = 0; j < 2; ++j) {
      float4 xv = xp[l*2 + j];
      float4 qv = qp[l*2 + j];
      float a = xv.x - qv.x, b = xv.y - qv.y, c = xv.z - qv.z, d = xv.w - qv.w;
      s = fmaf(a,a,s); s = fmaf(b,b,s); s = fmaf(c,c,s); s = fmaf(d,d,s);
    }
    #pragma unroll
    for (int m = 32; m; m >>= 1) s += __shfl_xor(s, m, 64);
    x2[mi] = s;
  }

  float acc[4][16];
  #pragma unroll
  for (int mi = 0; mi < 4; ++mi)
    #pragma unroll
    for (int jj = 0; jj < 16; ++jj) acc[mi][jj] = 0.f;

  // ---- GEMM: dot[token][code] over D in DK chunks, codes in KC halves
  for (int dt = 0; dt < DIM/DK; ++dt) {
    __syncthreads();   // previous readers done
    {
      // stage r_tile[32][32]: 1024 floats, float2 per thread
      int m = tid >> 4;
      int dd = (tid & 15) * 2;
      size_t gi = (size_t)(tok0 + m)*DIM + dt*DK + dd;
      float2 xv = *(const float2*)(x + gi);
      float2 qv = *(const float2*)(qsum + gi);
      r_tile[m*DK + dd]   = xv.x - qv.x;
      r_tile[m*DK + dd+1] = xv.y - qv.y;
    }
    #pragma unroll
    for (int kc = 0; kc < KCODES/KC; ++kc) {
      if (kc) __syncthreads();
      // stage cb_tile[512][32] (swizzled 16B granules within row)
      #pragma unroll
      for (int i = 0; i < (KC*DK/4)/THREADS; ++i) {
        int flat = tid + THREADS*i;      // 0..4095
        int row = flat >> 3;             // 0..511
        int g = flat & 7;
        float4 v = *(const float4*)(cb + (size_t)(kc*KC + row)*DIM + dt*DK + g*4);
        int gs = g ^ (row & 7);
        *(float4*)(&cb_tile[row*DK + gs*4]) = v;
      }
      __syncthreads();
      #pragma unroll
      for (int d4 = 0; d4 < 8; ++d4) {
        float4 rv[4];
        #pragma unroll
        for (int mi = 0; mi < 4; ++mi)
          rv[mi] = *(const float4*)(&r_tile[(w*4+mi)*DK + d4*4]);
        #pragma unroll
        for (int jj8 = 0; jj8 < 8; ++jj8) {
          int cl = l + 64*jj8;
          int gs = d4 ^ (cl & 7);
          float4 cv = *(const float4*)(&cb_tile[cl*DK + gs*4]);
          const int jj = kc*8 + jj8;
          #pragma unroll
          for (int mi = 0; mi < 4; ++mi) {
            acc[mi][jj] = fmaf(rv[mi].x, cv.x, acc[mi][jj]);
            acc[mi][jj] = fmaf(rv[mi].y, cv.y, acc[mi][jj]);
            acc[mi][jj] = fmaf(rv[mi].z, cv.z, acc[mi][jj]);
            acc[mi][jj] = fmaf(rv[mi].w, cv.w, acc[mi][jj]);
          }
        }
      }
    }
  }

  // ---- finalize: d2 = (x2 + c2) - 2*dot ; argmin (first-index ties) ; softmax probs
  float c2v[16];
  #pragma unroll
  for (int jj = 0; jj < 16; ++jj) c2v[jj] = c2[l + 64*jj];

  float zinv[4];
  #pragma unroll
  for (int mi = 0; mi < 4; ++mi) {
    float best = FLT_MAX;
    int bestc = 0x7fffffff;
    #pragma unroll
    for (int jj = 0; jj < 16; ++jj) {
      int c = l + 64*jj;
      float t1 = x2[mi] + c2v[jj];
      float d2 = t1 - 2.0f*acc[mi][jj];
      acc[mi][jj] = d2;
      if (d2 < best) { best = d2; bestc = c; }   // ascending c per lane -> first wins
    }
    #pragma unroll
    for (int m = 1; m < 64; m <<= 1) {
      float ob = __shfl_xor(best, m, 64);
      int oc = __shfl_xor(bestc, m, 64);
      if (ob < best || (ob == best && oc < bestc)) { best = ob; bestc = oc; }
    }
    // Z = sum exp(d2min - d2)
    float z = 0.f;
    #pragma unroll
    for (int jj = 0; jj < 16; ++jj) {
      float p = __expf(best - acc[mi][jj]);
      acc[mi][jj] = p;
      z += p;
    }
    #pragma unroll
    for (int m = 1; m < 64; m <<= 1) z += __shfl_xor(z, m, 64);
    zinv[mi] = 1.0f / z;
    if (l == 0) {
      int n = tok0 + w*4 + mi;
      codes_out[(size_t)n*LEVELS + level] = (float)bestc;
    }
  }
  // accumulate probs into LDS (codes unique per lane within wave; 8 waves -> ds atomics)
  #pragma unroll
  for (int jj = 0; jj < 16; ++jj) {
    float v = 0.f;
    #pragma unroll
    for (int mi = 0; mi < 4; ++mi) v = fmaf(acc[mi][jj], zinv[mi], v);
    atomicAdd(&probs_lds[l + 64*jj], v);
  }
  __syncthreads();
  for (int i = tid; i < KCODES; i += THREADS)
    atomicAdd(&probs_g[i], probs_lds[i]);
}

// ---------------------------------------------------------------- qsum += cb[idx]; commit partials
__global__ void update_kernel(const float* __restrict__ x,
                              float* __restrict__ qsum,
                              const float* __restrict__ cb,
                              const float* __restrict__ codes,
                              float* __restrict__ partials,
                              int level)
{
  const int tid = threadIdx.x;
  const int w = tid >> 6;          // 4 waves = 4 tokens per block
  const int l = tid & 63;
  const int n = blockIdx.x*4 + w;
  const int idx = (int)codes[(size_t)n*LEVELS + level];
  const float4* qrow = (const float4*)(cb + (size_t)idx*DIM);
  const float4* xrow = (const float4*)(x + (size_t)n*DIM);
  float4* srow = (float4*)(qsum + (size_t)n*DIM);
  float s = 0.f;
  #pragma unroll
  for (int j = 0; j < 2; ++j) {
    int e = l + 64*j;
    float4 q = qrow[e];
    float4 qs = srow[e];
    float4 xv = xrow[e];
    float4 nv = make_float4(qs.x+q.x, qs.y+q.y, qs.z+q.z, qs.w+q.w);
    srow[e] = nv;
    float a = xv.x - nv.x, b = xv.y - nv.y, c = xv.z - nv.z, d = xv.w - nv.w;
    s = fmaf(a,a,s); s = fmaf(b,b,s); s = fmaf(c,c,s); s = fmaf(d,d,s);
  }
  #pragma unroll
  for (int m = 32; m; m >>= 1) s += __shfl_xor(s, m, 64);
  __shared__ float wsum[4];
  if (l == 0) wsum[w] = s;
  __syncthreads();
  if (tid == 0)
    partials[level*NBLK_B + blockIdx.x] = (wsum[0]+wsum[1])+(wsum[2]+wsum[3]);
}

// ---------------------------------------------------------------- losses
__global__ void finalize_kernel(const float* __restrict__ ws, float* __restrict__ out) {
  const int tid = threadIdx.x;   // 1024 threads
  __shared__ float red[1024];
  float usum = 0.f, csum = 0.f;
  for (int lev = 0; lev < LEVELS; ++lev) {
    float a = ws[WS_PROBS + lev*KCODES + tid] * (1.0f/N_TOK);
    a = fmaxf(a, 1e-5f);
    red[tid] = a * logf(a);
    __syncthreads();
    for (int s = 512; s; s >>= 1) { if (tid < s) red[tid] += red[tid+s]; __syncthreads(); }
    if (tid == 0) usum += 6.9314718055994531f + red[0];   // logK - H = logK + sum a*log a
    __syncthreads();
    red[tid] = ws[WS_COMMIT + lev*NBLK_B + tid] + ws[WS_COMMIT + lev*NBLK_B + tid + 1024];
    __syncthreads();
    for (int s = 512; s; s >>= 1) { if (tid < s) red[tid] += red[tid+s]; __syncthreads(); }
    if (tid == 0) csum += red[0];
    __syncthreads();
  }
  if (tid == 0) {
    out[OUT_COMMIT] = (0.25f/3.0f) * (csum / (float)(N_TOK*DIM));
    out[OUT_USAGE]  = (1e-3f/3.0f) * usum;
  }
}

// ---------------------------------------------------------------- launch
extern "C" void kernel_launch(void* const* d_in, const int* in_sizes, int n_in,
                              void* d_out, int out_size, void* d_ws, size_t ws_size,
                              hipStream_t stream) {
  const float* x  = (const float*)d_in[0];
  const float* cb = (const float*)d_in[1];
  float* out = (float*)d_out;
  float* ws  = (float*)d_ws;

  // zero qsum region of d_out and the ws accumulators
  hipMemsetAsync(out, 0, (size_t)N_TOK*DIM*sizeof(float), stream);
  hipMemsetAsync(ws, 0, WS_TOTAL_BYTES, stream);

  c2_kernel<<<(LEVELS*KCODES)/4, 256, 0, stream>>>(cb, ws);

  const size_t smem = (size_t)(KC*DK + TM*DK + KCODES) * sizeof(float);  // 72 KB
  for (int level = 0; level < LEVELS; ++level) {
    const float* cbl = cb + (size_t)level*KCODES*DIM;
    rvq_level_kernel<<<N_TOK/TM, THREADS, smem, stream>>>(
        x, out, cbl, ws + WS_C2 + level*KCODES, ws + WS_PROBS + level*KCODES,
        out + OUT_CODES, level);
    update_kernel<<<N_TOK/4, 256, 0, stream>>>(
        x, out, cbl, out + OUT_CODES, ws + WS_COMMIT, level);
  }
  finalize_kernel<<<1, 1024, 0, stream>>>(ws, out);
}

// Round 2
// 350.382 us; speedup vs baseline: 1.5093x; 1.5093x over previous
//
#include <hip/hip_runtime.h>
#include <cfloat>

#define N_TOK 8192
#define DIM 512
#define KCODES 1024
#define LEVELS 3

// d_out float offsets
#define OUT_CODES (N_TOK*DIM)
#define OUT_COMMIT (OUT_CODES + N_TOK*LEVELS)
#define OUT_USAGE (OUT_COMMIT + 1)

// ws float offsets (small region)
#define WS_C2 0
#define WS_PROBS 3072
#define WS_COMMIT 6144
#define NBLK_B 2048
#define WS_X2 12288
// byte offsets (large region)
#define WS_CBH_BYTES 81920
#define WS_CBL_BYTES (WS_CBH_BYTES + (size_t)LEVELS*KCODES*DIM*2)   // 3227648
#define WS_DOT_BYTES (WS_CBL_BYTES + (size_t)LEVELS*KCODES*DIM*2)   // 6373376
#define WS_NEED (WS_DOT_BYTES + (size_t)N_TOK*KCODES*4)             // 39927808

typedef _Float16 f16x8 __attribute__((ext_vector_type(8)));
typedef _Float16 f16x4v __attribute__((ext_vector_type(4)));
typedef float f32x4 __attribute__((ext_vector_type(4)));

// ---------------------------------------------------------------- c2 = ||cb_k||^2
__global__ void c2_kernel(const float* __restrict__ cb, float* __restrict__ ws) {
  int row = blockIdx.x * 4 + (threadIdx.x >> 6);   // 0..3071
  int lane = threadIdx.x & 63;
  const float* p = cb + (size_t)row * DIM;
  float s = 0.f;
  #pragma unroll
  for (int j = 0; j < DIM/64; ++j) { float v = p[lane + 64*j]; s = fmaf(v, v, s); }
  #pragma unroll
  for (int m = 32; m; m >>= 1) s += __shfl_xor(s, m, 64);
  if (lane == 0) ws[WS_C2 + row] = s;
}

// ---------------------------------------------------------------- x2 init (level 0 residual = x)
__global__ void x2init_kernel(const float* __restrict__ x, float* __restrict__ x2) {
  int row = blockIdx.x * 4 + (threadIdx.x >> 6);
  int lane = threadIdx.x & 63;
  const float* p = x + (size_t)row * DIM;
  float s = 0.f;
  #pragma unroll
  for (int j = 0; j < DIM/64; ++j) { float v = p[lane + 64*j]; s = fmaf(v, v, s); }
  #pragma unroll
  for (int m = 32; m; m >>= 1) s += __shfl_xor(s, m, 64);
  if (lane == 0) x2[row] = s;
}

// ---------------------------------------------------------------- cb f32 -> f16 hi/lo split
__global__ void split_kernel(const float* __restrict__ cb,
                             _Float16* __restrict__ ch, _Float16* __restrict__ cl) {
  size_t i = ((size_t)blockIdx.x * 256 + threadIdx.x) * 4;
  float4 v = *(const float4*)(cb + i);
  f16x4v h, lo;
  h[0] = (_Float16)v.x; h[1] = (_Float16)v.y; h[2] = (_Float16)v.z; h[3] = (_Float16)v.w;
  lo[0] = (_Float16)(v.x - (float)h[0]);
  lo[1] = (_Float16)(v.y - (float)h[1]);
  lo[2] = (_Float16)(v.z - (float)h[2]);
  lo[3] = (_Float16)(v.w - (float)h[3]);
  *(f16x4v*)(ch + i) = h;
  *(f16x4v*)(cl + i) = lo;
}

// ---------------------------------------------------------------- split-f16 MFMA GEMM
// dot[n][c] = sum_d (x[n][d]-qsum[n][d]) * cb[c][d]
// block tile 128 tokens x 256 codes, BK=32, 4 waves (2M x 2N), wave = 4x8 tiles of 16x16x32
__launch_bounds__(256, 1)
__global__ void gemm_kernel(const float* __restrict__ x,
                            const float* __restrict__ qsum,
                            const _Float16* __restrict__ cbh,
                            const _Float16* __restrict__ cbl,
                            float* __restrict__ dot_out)
{
  extern __shared__ _Float16 sm[];
  _Float16* Ah = sm;            // [128][40]
  _Float16* Al = sm + 5120;
  _Float16* Bh = sm + 10240;    // [256][40]
  _Float16* Bl = sm + 20480;

  const int tid = threadIdx.x;
  const int bm = blockIdx.x >> 2, bn = blockIdx.x & 3;
  const int tok0 = bm * 128, cb0 = bn * 256;

  const int arow = tid >> 1, ahalf = tid & 1;   // A staging: row, 16-float half
  const int br = tid >> 2, bg = tid & 3;        // B staging: 4 granules/row

  f32x4 acc[4][8];
  #pragma unroll
  for (int i = 0; i < 4; ++i)
    #pragma unroll
    for (int j = 0; j < 8; ++j) acc[i][j] = (f32x4){0.f, 0.f, 0.f, 0.f};

  float4 xr[4], qr[4];
  uint4 bhreg[4], blreg[4];

  const float* xbase = x + (size_t)(tok0 + arow) * DIM + ahalf * 16;
  const float* qbase = qsum + (size_t)(tok0 + arow) * DIM + ahalf * 16;

  auto LOADK = [&](int kk) {
    const float4* xp = (const float4*)(xbase + kk * 32);
    const float4* qp = (const float4*)(qbase + kk * 32);
    #pragma unroll
    for (int i = 0; i < 4; ++i) { xr[i] = xp[i]; qr[i] = qp[i]; }
    #pragma unroll
    for (int i = 0; i < 4; ++i) {
      size_t off = (size_t)(cb0 + br + 64 * i) * DIM + kk * 32 + bg * 8;
      bhreg[i] = *(const uint4*)(cbh + off);
      blreg[i] = *(const uint4*)(cbl + off);
    }
  };
  auto WRITEK = [&]() {
    #pragma unroll
    for (int i = 0; i < 4; ++i) {
      float a = xr[i].x - qr[i].x, b = xr[i].y - qr[i].y;
      float c = xr[i].z - qr[i].z, d = xr[i].w - qr[i].w;
      f16x4v h, lo;
      h[0] = (_Float16)a; h[1] = (_Float16)b; h[2] = (_Float16)c; h[3] = (_Float16)d;
      lo[0] = (_Float16)(a - (float)h[0]);
      lo[1] = (_Float16)(b - (float)h[1]);
      lo[2] = (_Float16)(c - (float)h[2]);
      lo[3] = (_Float16)(d - (float)h[3]);
      int o = arow * 40 + ahalf * 16 + i * 4;
      *(f16x4v*)(Ah + o) = h;
      *(f16x4v*)(Al + o) = lo;
    }
    #pragma unroll
    for (int i = 0; i < 4; ++i) {
      int o = (br + 64 * i) * 40 + bg * 8;
      *(uint4*)(Bh + o) = bhreg[i];
      *(uint4*)(Bl + o) = blreg[i];
    }
  };

  const int w = tid >> 6, l = tid & 63;
  const int wm = w >> 1, wn = w & 1;
  const int l15 = l & 15, l4 = l >> 4;

  LOADK(0);
  for (int kk = 0; kk < DIM / 32; ++kk) {
    __syncthreads();            // previous compute's LDS reads done
    WRITEK();                   // stage slice kk
    __syncthreads();
    if (kk < DIM / 32 - 1) LOADK(kk + 1);   // prefetch overlaps MFMA below
    // compute slice kk
    f16x8 ah[4], al[4];
    #pragma unroll
    for (int mt = 0; mt < 4; ++mt) {
      int o = (wm * 64 + mt * 16 + l15) * 40 + l4 * 8;
      ah[mt] = *(const f16x8*)(Ah + o);
      al[mt] = *(const f16x8*)(Al + o);
    }
    #pragma unroll
    for (int nt = 0; nt < 8; ++nt) {
      int o = (wn * 128 + nt * 16 + l15) * 40 + l4 * 8;
      f16x8 bh = *(const f16x8*)(Bh + o);
      f16x8 bl = *(const f16x8*)(Bl + o);
      #pragma unroll
      for (int mt = 0; mt < 4; ++mt)
        acc[mt][nt] = __builtin_amdgcn_mfma_f32_16x16x32_f16(ah[mt], bh, acc[mt][nt], 0, 0, 0);
      #pragma unroll
      for (int mt = 0; mt < 4; ++mt)
        acc[mt][nt] = __builtin_amdgcn_mfma_f32_16x16x32_f16(ah[mt], bl, acc[mt][nt], 0, 0, 0);
      #pragma unroll
      for (int mt = 0; mt < 4; ++mt)
        acc[mt][nt] = __builtin_amdgcn_mfma_f32_16x16x32_f16(al[mt], bh, acc[mt][nt], 0, 0, 0);
    }
  }

  // store dot: C layout col = l&15, row = (l>>4)*4 + reg
  #pragma unroll
  for (int mt = 0; mt < 4; ++mt) {
    int row0 = tok0 + wm * 64 + mt * 16 + l4 * 4;
    #pragma unroll
    for (int nt = 0; nt < 8; ++nt) {
      int col = cb0 + wn * 128 + nt * 16 + l15;
      #pragma unroll
      for (int r = 0; r < 4; ++r)
        dot_out[(size_t)(row0 + r) * KCODES + col] = acc[mt][nt][r];
    }
  }
}

// ---------------------------------------------------------------- argmin + softmax epilogue
__launch_bounds__(512)
__global__ void epilogue_kernel(const float* __restrict__ dot,
                                const float* __restrict__ x2,
                                const float* __restrict__ c2,
                                float* __restrict__ probs_g,
                                float* __restrict__ codes_out,
                                int level)
{
  __shared__ float probs_lds[KCODES];
  const int tid = threadIdx.x, w = tid >> 6, l = tid & 63;
  const int tok0 = blockIdx.x * 32;
  for (int i = tid; i < KCODES; i += 512) probs_lds[i] = 0.f;
  __syncthreads();

  float c2v[16];
  #pragma unroll
  for (int jj = 0; jj < 16; ++jj) c2v[jj] = c2[l + 64*jj];
  float accp[16];
  #pragma unroll
  for (int jj = 0; jj < 16; ++jj) accp[jj] = 0.f;

  #pragma unroll
  for (int mi = 0; mi < 4; ++mi) {
    int n = tok0 + w*4 + mi;
    float x2n = x2[n];
    const float* dr = dot + (size_t)n * KCODES;
    float d2v[16];
    float best = FLT_MAX; int bestc = 0x7fffffff;
    #pragma unroll
    for (int jj = 0; jj < 16; ++jj) {
      int c = l + 64*jj;
      float t1 = x2n + c2v[jj];
      float d2 = t1 - 2.0f * dr[c];
      d2v[jj] = d2;
      if (d2 < best) { best = d2; bestc = c; }    // ascending c per lane -> first wins
    }
    #pragma unroll
    for (int m = 1; m < 64; m <<= 1) {
      float ob = __shfl_xor(best, m, 64);
      int oc = __shfl_xor(bestc, m, 64);
      if (ob < best || (ob == best && oc < bestc)) { best = ob; bestc = oc; }
    }
    float z = 0.f;
    float p16[16];
    #pragma unroll
    for (int jj = 0; jj < 16; ++jj) { float p = __expf(best - d2v[jj]); p16[jj] = p; z += p; }
    #pragma unroll
    for (int m = 1; m < 64; m <<= 1) z += __shfl_xor(z, m, 64);
    float zinv = 1.0f / z;
    if (l == 0) codes_out[(size_t)n*LEVELS + level] = (float)bestc;
    #pragma unroll
    for (int jj = 0; jj < 16; ++jj) accp[jj] = fmaf(p16[jj], zinv, accp[jj]);
  }
  #pragma unroll
  for (int jj = 0; jj < 16; ++jj) atomicAdd(&probs_lds[l + 64*jj], accp[jj]);
  __syncthreads();
  for (int i = tid; i < KCODES; i += 512)
    atomicAdd(&probs_g[i], probs_lds[i]);
}

// ---------------------------------------------------------------- qsum += cb[idx]; commit + x2_next
__global__ void update_kernel(const float* __restrict__ x,
                              float* __restrict__ qsum,
                              const float* __restrict__ cb,
                              const float* __restrict__ codes,
                              float* __restrict__ partials,
                              float* __restrict__ x2out,
                              int level)
{
  const int tid = threadIdx.x;
  const int w = tid >> 6;
  const int l = tid & 63;
  const int n = blockIdx.x*4 + w;
  const int idx = (int)codes[(size_t)n*LEVELS + level];
  const float4* qrow = (const float4*)(cb + (size_t)idx*DIM);
  const float4* xrow = (const float4*)(x + (size_t)n*DIM);
  float4* srow = (float4*)(qsum + (size_t)n*DIM);
  float s = 0.f;
  #pragma unroll
  for (int j = 0; j < 2; ++j) {
    int e = l + 64*j;
    float4 q = qrow[e];
    float4 qs = srow[e];
    float4 xv = xrow[e];
    float4 nv = make_float4(qs.x+q.x, qs.y+q.y, qs.z+q.z, qs.w+q.w);
    srow[e] = nv;
    float a = xv.x - nv.x, b = xv.y - nv.y, c = xv.z - nv.z, d = xv.w - nv.w;
    s = fmaf(a,a,s); s = fmaf(b,b,s); s = fmaf(c,c,s); s = fmaf(d,d,s);
  }
  #pragma unroll
  for (int m = 32; m; m >>= 1) s += __shfl_xor(s, m, 64);
  __shared__ float wsum[4];
  if (l == 0) { wsum[w] = s; x2out[n] = s; }
  __syncthreads();
  if (tid == 0)
    partials[level*NBLK_B + blockIdx.x] = (wsum[0]+wsum[1])+(wsum[2]+wsum[3]);
}

// ---------------------------------------------------------------- losses
__global__ void finalize_kernel(const float* __restrict__ ws, float* __restrict__ out) {
  const int tid = threadIdx.x;   // 1024 threads
  __shared__ float red[1024];
  float usum = 0.f, csum = 0.f;
  for (int lev = 0; lev < LEVELS; ++lev) {
    float a = ws[WS_PROBS + lev*KCODES + tid] * (1.0f/N_TOK);
    a = fmaxf(a, 1e-5f);
    red[tid] = a * logf(a);
    __syncthreads();
    for (int s = 512; s; s >>= 1) { if (tid < s) red[tid] += red[tid+s]; __syncthreads(); }
    if (tid == 0) usum += 6.9314718055994531f + red[0];
    __syncthreads();
    red[tid] = ws[WS_COMMIT + lev*NBLK_B + tid] + ws[WS_COMMIT + lev*NBLK_B + tid + 1024];
    __syncthreads();
    for (int s = 512; s; s >>= 1) { if (tid < s) red[tid] += red[tid+s]; __syncthreads(); }
    if (tid == 0) csum += red[0];
    __syncthreads();
  }
  if (tid == 0) {
    out[OUT_COMMIT] = (0.25f/3.0f) * (csum / (float)(N_TOK*DIM));
    out[OUT_USAGE]  = (1e-3f/3.0f) * usum;
  }
}

// ---------------------------------------------------------------- fallback (round-1 f32 kernel)
#define TM 32
#define DK 32
#define KC 512
#define THREADS 512
__launch_bounds__(THREADS, 2)
__global__ void rvq_level_kernel(const float* __restrict__ x,
                                 const float* __restrict__ qsum,
                                 const float* __restrict__ cb,
                                 const float* __restrict__ c2,
                                 float* __restrict__ probs_g,
                                 float* __restrict__ codes_out,
                                 int level)
{
  extern __shared__ float smemf[];
  float* cb_tile   = smemf;
  float* r_tile    = smemf + KC*DK;
  float* probs_lds = smemf + KC*DK + TM*DK;

  const int tid = threadIdx.x;
  const int w = tid >> 6;
  const int l = tid & 63;
  const int tok0 = blockIdx.x * TM;

  for (int i = tid; i < KCODES; i += THREADS) probs_lds[i] = 0.f;

  float x2[4];
  #pragma unroll
  for (int mi = 0; mi < 4; ++mi) {
    int n = tok0 + w*4 + mi;
    const float4* xp = (const float4*)(x + (size_t)n*DIM);
    const float4* qp = (const float4*)(qsum + (size_t)n*DIM);
    float s = 0.f;
    #pragma unroll
    for (int j = 0; j < 2; ++j) {
      float4 xv = xp[l*2 + j];
      float4 qv = qp[l*2 + j];
      float a = xv.x - qv.x, b = xv.y - qv.y, c = xv.z - qv.z, d = xv.w - qv.w;
      s = fmaf(a,a,s); s = fmaf(b,b,s); s = fmaf(c,c,s); s = fmaf(d,d,s);
    }
    #pragma unroll
    for (int m = 32; m; m >>= 1) s += __shfl_xor(s, m, 64);
    x2[mi] = s;
  }

  float acc[4][16];
  #pragma unroll
  for (int mi = 0; mi < 4; ++mi)
    #pragma unroll
    for (int jj = 0; jj < 16; ++jj) acc[mi][jj] = 0.f;

  for (int dt = 0; dt < DIM/DK; ++dt) {
    __syncthreads();
    {
      int m = tid >> 4;
      int dd = (tid & 15) * 2;
      size_t gi = (size_t)(tok0 + m)*DIM + dt*DK + dd;
      float2 xv = *(const float2*)(x + gi);
      float2 qv = *(const float2*)(qsum + gi);
      r_tile[m*DK + dd]   = xv.x - qv.x;
      r_tile[m*DK + dd+1] = xv.y - qv.y;
    }
    #pragma unroll
    for (int kc = 0; kc < KCODES/KC; ++kc) {
      if (kc) __syncthreads();
      #pragma unroll
      for (int i = 0; i < (KC*DK/4)/THREADS; ++i) {
        int flat = tid + THREADS*i;
        int row = flat >> 3;
        int g = flat & 7;
        float4 v = *(const float4*)(cb + (size_t)(kc*KC + row)*DIM + dt*DK + g*4);
        int gs = g ^ (row & 7);
        *(float4*)(&cb_tile[row*DK + gs*4]) = v;
      }
      __syncthreads();
      #pragma unroll
      for (int d4 = 0; d4 < 8; ++d4) {
        float4 rv[4];
        #pragma unroll
        for (int mi = 0; mi < 4; ++mi)
          rv[mi] = *(const float4*)(&r_tile[(w*4+mi)*DK + d4*4]);
        #pragma unroll
        for (int jj8 = 0; jj8 < 8; ++jj8) {
          int cl = l + 64*jj8;
          int gs = d4 ^ (cl & 7);
          float4 cv = *(const float4*)(&cb_tile[cl*DK + gs*4]);
          const int jj = kc*8 + jj8;
          #pragma unroll
          for (int mi = 0; mi < 4; ++mi) {
            acc[mi][jj] = fmaf(rv[mi].x, cv.x, acc[mi][jj]);
            acc[mi][jj] = fmaf(rv[mi].y, cv.y, acc[mi][jj]);
            acc[mi][jj] = fmaf(rv[mi].z, cv.z, acc[mi][jj]);
            acc[mi][jj] = fmaf(rv[mi].w, cv.w, acc[mi][jj]);
          }
        }
      }
    }
  }

  float c2v[16];
  #pragma unroll
  for (int jj = 0; jj < 16; ++jj) c2v[jj] = c2[l + 64*jj];

  float zinv[4];
  #pragma unroll
  for (int mi = 0; mi < 4; ++mi) {
    float best = FLT_MAX;
    int bestc = 0x7fffffff;
    #pragma unroll
    for (int jj = 0; jj < 16; ++jj) {
      int c = l + 64*jj;
      float t1 = x2[mi] + c2v[jj];
      float d2 = t1 - 2.0f*acc[mi][jj];
      acc[mi][jj] = d2;
      if (d2 < best) { best = d2; bestc = c; }
    }
    #pragma unroll
    for (int m = 1; m < 64; m <<= 1) {
      float ob = __shfl_xor(best, m, 64);
      int oc = __shfl_xor(bestc, m, 64);
      if (ob < best || (ob == best && oc < bestc)) { best = ob; bestc = oc; }
    }
    float z = 0.f;
    #pragma unroll
    for (int jj = 0; jj < 16; ++jj) {
      float p = __expf(best - acc[mi][jj]);
      acc[mi][jj] = p;
      z += p;
    }
    #pragma unroll
    for (int m = 1; m < 64; m <<= 1) z += __shfl_xor(z, m, 64);
    zinv[mi] = 1.0f / z;
    if (l == 0) {
      int n = tok0 + w*4 + mi;
      codes_out[(size_t)n*LEVELS + level] = (float)bestc;
    }
  }
  #pragma unroll
  for (int jj = 0; jj < 16; ++jj) {
    float v = 0.f;
    #pragma unroll
    for (int mi = 0; mi < 4; ++mi) v = fmaf(acc[mi][jj], zinv[mi], v);
    atomicAdd(&probs_lds[l + 64*jj], v);
  }
  __syncthreads();
  for (int i = tid; i < KCODES; i += THREADS)
    atomicAdd(&probs_g[i], probs_lds[i]);
}

// ---------------------------------------------------------------- launch
extern "C" void kernel_launch(void* const* d_in, const int* in_sizes, int n_in,
                              void* d_out, int out_size, void* d_ws, size_t ws_size,
                              hipStream_t stream) {
  const float* x  = (const float*)d_in[0];
  const float* cb = (const float*)d_in[1];
  float* out = (float*)d_out;
  float* ws  = (float*)d_ws;

  hipMemsetAsync(out, 0, (size_t)N_TOK*DIM*sizeof(float), stream);

  if (ws_size >= WS_NEED) {
    hipMemsetAsync((char*)d_ws + WS_PROBS*4, 0, LEVELS*KCODES*4, stream);
    _Float16* cbh = (_Float16*)((char*)d_ws + WS_CBH_BYTES);
    _Float16* cbl = (_Float16*)((char*)d_ws + WS_CBL_BYTES);
    float* dotws  = (float*)((char*)d_ws + WS_DOT_BYTES);

    split_kernel<<<(LEVELS*KCODES*DIM/4)/256, 256, 0, stream>>>(cb, cbh, cbl);
    c2_kernel<<<(LEVELS*KCODES)/4, 256, 0, stream>>>(cb, ws);
    x2init_kernel<<<N_TOK/4, 256, 0, stream>>>(x, ws + WS_X2);

    for (int level = 0; level < LEVELS; ++level) {
      gemm_kernel<<<256, 256, 61440, stream>>>(
          x, out, cbh + (size_t)level*KCODES*DIM, cbl + (size_t)level*KCODES*DIM, dotws);
      epilogue_kernel<<<N_TOK/32, 512, 0, stream>>>(
          dotws, ws + WS_X2, ws + WS_C2 + level*KCODES, ws + WS_PROBS + level*KCODES,
          out + OUT_CODES, level);
      update_kernel<<<N_TOK/4, 256, 0, stream>>>(
          x, out, cb + (size_t)level*KCODES*DIM, out + OUT_CODES,
          ws + WS_COMMIT, ws + WS_X2, level);
    }
    finalize_kernel<<<1, 1024, 0, stream>>>(ws, out);
  } else {
    // fallback: round-1 f32 path (requires only ~80 KB ws)
    hipMemsetAsync(ws, 0, (WS_X2 + N_TOK)*4 < ws_size ? 12288*4 : 12288*4, stream);
    c2_kernel<<<(LEVELS*KCODES)/4, 256, 0, stream>>>(cb, ws);
    const size_t smem = (size_t)(KC*DK + TM*DK + KCODES) * sizeof(float);
    for (int level = 0; level < LEVELS; ++level) {
      const float* cbl2 = cb + (size_t)level*KCODES*DIM;
      rvq_level_kernel<<<N_TOK/TM, THREADS, smem, stream>>>(
          x, out, cbl2, ws + WS_C2 + level*KCODES, ws + WS_PROBS + level*KCODES,
          out + OUT_CODES, level);
      update_kernel<<<N_TOK/4, 256, 0, stream>>>(
          x, out, cbl2, out + OUT_CODES, ws + WS_COMMIT, ws + WS_X2, level);
    }
    finalize_kernel<<<1, 1024, 0, stream>>>(ws, out);
  }
}

// Round 4
// 310.631 us; speedup vs baseline: 1.7024x; 1.1280x over previous
//
#include <hip/hip_runtime.h>
#include <cfloat>

#define N_TOK 8192
#define DIM 512
#define KCODES 1024
#define LEVELS 3

// d_out float offsets
#define OUT_CODES (N_TOK*DIM)
#define OUT_COMMIT (OUT_CODES + N_TOK*LEVELS)
#define OUT_USAGE (OUT_COMMIT + 1)

// ws float offsets (small region)
#define WS_C2 0
#define WS_PROBS 3072
#define WS_COMMIT 6144
#define NBLK_B 2048
#define WS_SMALL_BYTES 49152
// byte offsets (large region)
#define WS_CBH_BYTES 81920
#define WS_CBL_BYTES (WS_CBH_BYTES + (size_t)LEVELS*KCODES*DIM*2)

typedef _Float16 f16x8 __attribute__((ext_vector_type(8)));
typedef _Float16 f16x2 __attribute__((ext_vector_type(2)));
typedef _Float16 f16x4v __attribute__((ext_vector_type(4)));
typedef float f32x4 __attribute__((ext_vector_type(4)));

// ---------------------------------------------------------------- c2 = ||cb_k||^2
__global__ void c2_kernel(const float* __restrict__ cb, float* __restrict__ ws) {
  int row = blockIdx.x * 4 + (threadIdx.x >> 6);   // 0..3071
  int lane = threadIdx.x & 63;
  const float* p = cb + (size_t)row * DIM;
  float s = 0.f;
  #pragma unroll
  for (int j = 0; j < DIM/64; ++j) { float v = p[lane + 64*j]; s = fmaf(v, v, s); }
  #pragma unroll
  for (int m = 32; m; m >>= 1) s += __shfl_xor(s, m, 64);
  if (lane == 0) ws[WS_C2 + row] = s;
}

// ---------------------------------------------------------------- cb f32 -> f16 hi/lo split
__global__ void split_kernel(const float* __restrict__ cb,
                             _Float16* __restrict__ ch, _Float16* __restrict__ cl) {
  size_t i = ((size_t)blockIdx.x * 256 + threadIdx.x) * 4;
  float4 v = *(const float4*)(cb + i);
  f16x4v h, lo;
  h[0] = (_Float16)v.x; h[1] = (_Float16)v.y; h[2] = (_Float16)v.z; h[3] = (_Float16)v.w;
  lo[0] = (_Float16)(v.x - (float)h[0]);
  lo[1] = (_Float16)(v.y - (float)h[1]);
  lo[2] = (_Float16)(v.z - (float)h[2]);
  lo[3] = (_Float16)(v.w - (float)h[3]);
  *(f16x4v*)(ch + i) = h;
  *(f16x4v*)(cl + i) = lo;
}

// ---------------------------------------------------------------- fused level kernel
// 512 threads = 8 waves. Block = 32 tokens x 1024 codes, K=512 in 16 steps of 32.
// Wave w owns codes [w*128, w*128+128): mt=2 M-tiles x nt=8 N-tiles of 16x16x32.
// Single-buffer A staging, two barriers per k-step (canonical safe pattern);
// k+1 global loads prefetched into registers so HBM latency hides under MFMA.
__launch_bounds__(512, 2)
__global__ void rvq_fused_kernel(const float* __restrict__ x,
                                 float* __restrict__ qsum,
                                 const _Float16* __restrict__ cbh,
                                 const _Float16* __restrict__ cbl,
                                 const float* __restrict__ cbf,
                                 const float* __restrict__ c2,
                                 float* __restrict__ probs_g,
                                 float* __restrict__ codes_out,
                                 float* __restrict__ partials,
                                 int level)
{
  __shared__ _Float16 Ah[32*40];
  __shared__ _Float16 Al[32*40];
  __shared__ float c2s[KCODES];
  __shared__ float probs_lds[KCODES];
  __shared__ float x2s[32];
  __shared__ float wredd[8][32];
  __shared__ int   wredi[8][32];
  __shared__ float wredz[8][32];
  __shared__ int   fcode[32];
  __shared__ float wpart[8];

  const int tid = threadIdx.x;
  const int w = tid >> 6, l = tid & 63;
  const int l15 = l & 15, l4 = l >> 4;
  const int tok0 = blockIdx.x * 32;
  const int slab = w * 128;

  for (int i = tid; i < KCODES; i += 512) { c2s[i] = c2[i]; probs_lds[i] = 0.f; }

  // ---- A staging setup (thread -> row tid>>4, 2 dims per k-step)
  const int srow = tid >> 4;
  const int sdd  = (tid & 15) * 2;
  const float* xrow_s = x + (size_t)(tok0 + srow) * DIM + sdd;
  const float* qrow_s = qsum + (size_t)(tok0 + srow) * DIM + sdd;
  float x2p = 0.f;
  float2 xv_r, qv_r;

  auto LOADR = [&](int k) {
    xv_r = *(const float2*)(xrow_s + k * 32);
    if (level) qv_r = *(const float2*)(qrow_s + k * 32);
  };
  auto STORE = [&]() {
    float a0, a1;
    if (level) { a0 = xv_r.x - qv_r.x; a1 = xv_r.y - qv_r.y; }
    else       { a0 = xv_r.x;          a1 = xv_r.y; }
    _Float16 h0 = (_Float16)a0, h1 = (_Float16)a1;
    f16x2 hv; hv[0] = h0; hv[1] = h1;
    f16x2 lv; lv[0] = (_Float16)(a0 - (float)h0); lv[1] = (_Float16)(a1 - (float)h1);
    *(f16x2*)(&Ah[srow * 40 + sdd]) = hv;
    *(f16x2*)(&Al[srow * 40 + sdd]) = lv;
    x2p = fmaf(a1, a1, fmaf(a0, a0, x2p));
  };

  f32x4 acc[2][8];
  #pragma unroll
  for (int mt = 0; mt < 2; ++mt)
    #pragma unroll
    for (int nt = 0; nt < 8; ++nt) acc[mt][nt] = (f32x4){0.f, 0.f, 0.f, 0.f};

  const _Float16* bhbase = cbh + (size_t)(slab + l15) * DIM + l4 * 8;
  const _Float16* blbase = cbl + (size_t)(slab + l15) * DIM + l4 * 8;

  LOADR(0);
  for (int k = 0; k < 16; ++k) {
    __syncthreads();            // previous k's LDS reads complete
    STORE();                    // stage slice k (single buffer)
    __syncthreads();            // staging visible
    if (k < 15) LOADR(k + 1);   // global prefetch overlaps MFMA below
    // B frags direct from global (L2): rows slab+nt*16+l15, cols k*32 + l4*8
    f16x8 bh[8], bl[8];
    #pragma unroll
    for (int nt = 0; nt < 8; ++nt) {
      size_t off = (size_t)nt * 16 * DIM + k * 32;
      bh[nt] = *(const f16x8*)(bhbase + off);
      bl[nt] = *(const f16x8*)(blbase + off);
    }
    // A frags from LDS
    f16x8 ah[2], al[2];
    #pragma unroll
    for (int mt = 0; mt < 2; ++mt) {
      int o = (mt * 16 + l15) * 40 + l4 * 8;
      ah[mt] = *(const f16x8*)(&Ah[o]);
      al[mt] = *(const f16x8*)(&Al[o]);
    }
    // 3-pass split-f16 MFMA; per-acc-element order hh, hl, lh (bitwise == R2/R3)
    #pragma unroll
    for (int nt = 0; nt < 8; ++nt) {
      #pragma unroll
      for (int mt = 0; mt < 2; ++mt)
        acc[mt][nt] = __builtin_amdgcn_mfma_f32_16x16x32_f16(ah[mt], bh[nt], acc[mt][nt], 0, 0, 0);
      #pragma unroll
      for (int mt = 0; mt < 2; ++mt)
        acc[mt][nt] = __builtin_amdgcn_mfma_f32_16x16x32_f16(ah[mt], bl[nt], acc[mt][nt], 0, 0, 0);
      #pragma unroll
      for (int mt = 0; mt < 2; ++mt)
        acc[mt][nt] = __builtin_amdgcn_mfma_f32_16x16x32_f16(al[mt], bh[nt], acc[mt][nt], 0, 0, 0);
    }
  }

  // ---- finalize x2 per token (reduce the 16-thread staging group)
  #pragma unroll
  for (int m = 8; m; m >>= 1) x2p += __shfl_xor(x2p, m, 64);
  __syncthreads();              // last k's LDS reads done; safe to reuse nothing, paranoia
  if ((tid & 15) == 0) x2s[srow] = x2p;
  __syncthreads();

  // ---- epilogue: d2, argmin (first-index ties), softmax probs
  float c2v[8];
  #pragma unroll
  for (int nt = 0; nt < 8; ++nt) c2v[nt] = c2s[slab + nt * 16 + l15];

  // pass 1: per-wave argmin over this wave's 128 codes
  #pragma unroll
  for (int mt = 0; mt < 2; ++mt) {
    #pragma unroll
    for (int r = 0; r < 4; ++r) {
      int t = mt * 16 + l4 * 4 + r;
      float x2t = x2s[t];
      float best = FLT_MAX; int bc = 0x7fffffff;
      #pragma unroll
      for (int nt = 0; nt < 8; ++nt) {
        float t1 = x2t + c2v[nt];
        float d2 = t1 - 2.0f * acc[mt][nt][r];
        acc[mt][nt][r] = d2;
        int c = slab + nt * 16 + l15;
        if (d2 < best) { best = d2; bc = c; }   // ascending c per lane -> first wins
      }
      #pragma unroll
      for (int m = 1; m < 16; m <<= 1) {
        float ob = __shfl_xor(best, m, 64);
        int oc = __shfl_xor(bc, m, 64);
        if (ob < best || (ob == best && oc < bc)) { best = ob; bc = oc; }
      }
      if (l15 == 0) { wredd[w][t] = best; wredi[w][t] = bc; }
    }
  }
  __syncthreads();

  // pass 2: combine the 8 waves' partial argmins
  float bfin[2][4];
  #pragma unroll
  for (int mt = 0; mt < 2; ++mt) {
    #pragma unroll
    for (int r = 0; r < 4; ++r) {
      int t = mt * 16 + l4 * 4 + r;
      float best = FLT_MAX; int bc = 0x7fffffff;
      #pragma unroll
      for (int wv = 0; wv < 8; ++wv) {
        float ob = wredd[wv][t]; int oc = wredi[wv][t];
        if (ob < best || (ob == best && oc < bc)) { best = ob; bc = oc; }
      }
      bfin[mt][r] = best;
      if (w == 0 && l15 == 0) {
        fcode[t] = bc;
        codes_out[(size_t)(tok0 + t) * LEVELS + level] = (float)bc;
      }
    }
  }
  __syncthreads();

  // pass 3: Z = sum exp(d2min - d2)
  #pragma unroll
  for (int mt = 0; mt < 2; ++mt) {
    #pragma unroll
    for (int r = 0; r < 4; ++r) {
      int t = mt * 16 + l4 * 4 + r;
      float z = 0.f;
      #pragma unroll
      for (int nt = 0; nt < 8; ++nt) {
        float p = __expf(bfin[mt][r] - acc[mt][nt][r]);
        acc[mt][nt][r] = p;
        z += p;
      }
      #pragma unroll
      for (int m = 1; m < 16; m <<= 1) z += __shfl_xor(z, m, 64);
      if (l15 == 0) wredz[w][t] = z;
    }
  }
  __syncthreads();

  float zin[2][4];
  #pragma unroll
  for (int mt = 0; mt < 2; ++mt) {
    #pragma unroll
    for (int r = 0; r < 4; ++r) {
      int t = mt * 16 + l4 * 4 + r;
      float Z = 0.f;
      #pragma unroll
      for (int wv = 0; wv < 8; ++wv) Z += wredz[wv][t];
      zin[mt][r] = 1.0f / Z;
    }
  }
  __syncthreads();

  // probs accumulation: each wave owns its 128-code slab (no conflicts)
  #pragma unroll
  for (int nt = 0; nt < 8; ++nt) {
    float v = 0.f;
    #pragma unroll
    for (int mt = 0; mt < 2; ++mt)
      #pragma unroll
      for (int r = 0; r < 4; ++r) v = fmaf(acc[mt][nt][r], zin[mt][r], v);
    v += __shfl_xor(v, 16, 64);
    v += __shfl_xor(v, 32, 64);
    if (l4 == 0) probs_lds[slab + nt * 16 + l15] += v;
  }
  __syncthreads();
  for (int i = tid; i < KCODES; i += 512) atomicAdd(&probs_g[i], probs_lds[i]);
  __syncthreads();

  // ---- fused update: qsum += cb[code]; commit partial
  {
    const int urow = tid >> 4;
    const int uc = (tid & 15) * 4;
    const int code = fcode[urow];
    const float* cbr = cbf + (size_t)code * DIM;
    const float* xr = x + (size_t)(tok0 + urow) * DIM;
    float* qr = qsum + (size_t)(tok0 + urow) * DIM;
    float sq = 0.f;
    #pragma unroll
    for (int j = 0; j < 8; ++j) {
      int d = uc + j * 64;
      float4 cv = *(const float4*)(cbr + d);
      float4 nv;
      if (level) {
        float4 qv = *(const float4*)(qr + d);
        nv = make_float4(qv.x + cv.x, qv.y + cv.y, qv.z + cv.z, qv.w + cv.w);
      } else nv = cv;
      *(float4*)(qr + d) = nv;
      float4 xv = *(const float4*)(xr + d);
      float a = xv.x - nv.x, b = xv.y - nv.y, c = xv.z - nv.z, e = xv.w - nv.w;
      sq = fmaf(a, a, sq); sq = fmaf(b, b, sq); sq = fmaf(c, c, sq); sq = fmaf(e, e, sq);
    }
    #pragma unroll
    for (int m = 32; m; m >>= 1) sq += __shfl_xor(sq, m, 64);
    if (l == 0) wpart[w] = sq;
    __syncthreads();
    if (tid == 0) {
      float s = 0.f;
      #pragma unroll
      for (int i = 0; i < 8; ++i) s += wpart[i];
      partials[level * NBLK_B + blockIdx.x] = s;
    }
  }
}

// ---------------------------------------------------------------- losses
__global__ void finalize_kernel(const float* __restrict__ ws, float* __restrict__ out) {
  const int tid = threadIdx.x;   // 1024 threads
  __shared__ float red[1024];
  float usum = 0.f, csum = 0.f;
  for (int lev = 0; lev < LEVELS; ++lev) {
    float a = ws[WS_PROBS + lev*KCODES + tid] * (1.0f/N_TOK);
    a = fmaxf(a, 1e-5f);
    red[tid] = a * logf(a);
    __syncthreads();
    for (int s = 512; s; s >>= 1) { if (tid < s) red[tid] += red[tid+s]; __syncthreads(); }
    if (tid == 0) usum += 6.9314718055994531f + red[0];
    __syncthreads();
    red[tid] = ws[WS_COMMIT + lev*NBLK_B + tid] + ws[WS_COMMIT + lev*NBLK_B + tid + 1024];
    __syncthreads();
    for (int s = 512; s; s >>= 1) { if (tid < s) red[tid] += red[tid+s]; __syncthreads(); }
    if (tid == 0) csum += red[0];
    __syncthreads();
  }
  if (tid == 0) {
    out[OUT_COMMIT] = (0.25f/3.0f) * (csum / (float)(N_TOK*DIM));
    out[OUT_USAGE]  = (1e-3f/3.0f) * usum;
  }
}

// ---------------------------------------------------------------- launch
extern "C" void kernel_launch(void* const* d_in, const int* in_sizes, int n_in,
                              void* d_out, int out_size, void* d_ws, size_t ws_size,
                              hipStream_t stream) {
  const float* x  = (const float*)d_in[0];
  const float* cb = (const float*)d_in[1];
  float* out = (float*)d_out;
  float* ws  = (float*)d_ws;

  // zero probs + commit-partial accumulators (c2 region harmlessly included)
  hipMemsetAsync(d_ws, 0, WS_SMALL_BYTES, stream);

  _Float16* cbh = (_Float16*)((char*)d_ws + WS_CBH_BYTES);
  _Float16* cbl = (_Float16*)((char*)d_ws + WS_CBL_BYTES);

  split_kernel<<<(LEVELS*KCODES*DIM/4)/256, 256, 0, stream>>>(cb, cbh, cbl);
  c2_kernel<<<(LEVELS*KCODES)/4, 256, 0, stream>>>(cb, ws);

  for (int level = 0; level < LEVELS; ++level) {
    rvq_fused_kernel<<<N_TOK/32, 512, 0, stream>>>(
        x, out,
        cbh + (size_t)level*KCODES*DIM, cbl + (size_t)level*KCODES*DIM,
        cb + (size_t)level*KCODES*DIM,
        ws + WS_C2 + level*KCODES, ws + WS_PROBS + level*KCODES,
        out + OUT_CODES, ws + WS_COMMIT, level);
  }
  finalize_kernel<<<1, 1024, 0, stream>>>(ws, out);
}

// Round 5
// 288.589 us; speedup vs baseline: 1.8324x; 1.0764x over previous
//
#include <hip/hip_runtime.h>
#include <cfloat>

#define N_TOK 8192
#define DIM 512
#define KCODES 1024
#define LEVELS 3

// d_out float offsets
#define OUT_CODES (N_TOK*DIM)
#define OUT_COMMIT (OUT_CODES + N_TOK*LEVELS)
#define OUT_USAGE (OUT_COMMIT + 1)

// ws float offsets (small region)
#define WS_C2 0
#define WS_PROBS 3072
#define WS_COMMIT 6144
#define NBLK_B 2048
#define WS_SMALL_BYTES 49152
// byte offsets (large region)
#define WS_CBH_BYTES 81920
#define WS_CBL_BYTES (WS_CBH_BYTES + (size_t)LEVELS*KCODES*DIM*2)

#define APAD 520   // A LDS row stride in f16 (1040B = 260 words ≡ 4 mod 32 -> uniform banks)

typedef _Float16 f16x8 __attribute__((ext_vector_type(8)));
typedef _Float16 f16x4v __attribute__((ext_vector_type(4)));
typedef float f32x4 __attribute__((ext_vector_type(4)));

// ---------------------------------------------------------------- c2 = ||cb_k||^2
__global__ void c2_kernel(const float* __restrict__ cb, float* __restrict__ ws) {
  int row = blockIdx.x * 4 + (threadIdx.x >> 6);   // 0..3071
  int lane = threadIdx.x & 63;
  const float* p = cb + (size_t)row * DIM;
  float s = 0.f;
  #pragma unroll
  for (int j = 0; j < DIM/64; ++j) { float v = p[lane + 64*j]; s = fmaf(v, v, s); }
  #pragma unroll
  for (int m = 32; m; m >>= 1) s += __shfl_xor(s, m, 64);
  if (lane == 0) ws[WS_C2 + row] = s;
}

// ---------------------------------------------------------------- cb f32 -> f16 hi/lo split
__global__ void split_kernel(const float* __restrict__ cb,
                             _Float16* __restrict__ ch, _Float16* __restrict__ cl) {
  size_t i = ((size_t)blockIdx.x * 256 + threadIdx.x) * 4;
  float4 v = *(const float4*)(cb + i);
  f16x4v h, lo;
  h[0] = (_Float16)v.x; h[1] = (_Float16)v.y; h[2] = (_Float16)v.z; h[3] = (_Float16)v.w;
  lo[0] = (_Float16)(v.x - (float)h[0]);
  lo[1] = (_Float16)(v.y - (float)h[1]);
  lo[2] = (_Float16)(v.z - (float)h[2]);
  lo[3] = (_Float16)(v.w - (float)h[3]);
  *(f16x4v*)(ch + i) = h;
  *(f16x4v*)(cl + i) = lo;
}

// ---------------------------------------------------------------- fused level kernel
// 512 threads = 8 waves. Block = 32 tokens x 1024 codes, K=512 in 16 steps of 32.
// Wave w owns codes [w*128, w*128+128): mt=2 M-tiles x nt=8 N-tiles of 16x16x32.
// Full residual hi/lo staged in LDS ONCE (no barriers in K-loop); B streamed
// from global (L2-resident) with register double-buffer pipelined one step ahead.
__launch_bounds__(512, 2)
__global__ void rvq_fused_kernel(const float* __restrict__ x,
                                 float* __restrict__ qsum,
                                 const _Float16* __restrict__ cbh,
                                 const _Float16* __restrict__ cbl,
                                 const float* __restrict__ cbf,
                                 const float* __restrict__ c2,
                                 float* __restrict__ probs_g,
                                 float* __restrict__ codes_out,
                                 float* __restrict__ partials,
                                 int level)
{
  __shared__ _Float16 Ah[32*APAD];
  __shared__ _Float16 Al[32*APAD];
  __shared__ float c2s[KCODES];
  __shared__ float probs_lds[KCODES];
  __shared__ float x2s[32];
  __shared__ float wredd[8][32];
  __shared__ int   wredi[8][32];
  __shared__ float wredz[8][32];
  __shared__ int   fcode[32];
  __shared__ float wpart[8];

  const int tid = threadIdx.x;
  const int w = tid >> 6, l = tid & 63;
  const int l15 = l & 15, l4 = l >> 4;
  const int tok0 = blockIdx.x * 32;
  const int slab = w * 128;

  for (int i = tid; i < KCODES; i += 512) { c2s[i] = c2[i]; probs_lds[i] = 0.f; }

  // ---- one-time A staging: residual hi/lo split -> LDS, fused x2
  {
    const int srow = tid >> 4;          // 0..31
    const int sc4 = (tid & 15) * 4;     // float4 col base
    const float* xr_s = x + (size_t)(tok0 + srow) * DIM;
    const float* qr_s = qsum + (size_t)(tok0 + srow) * DIM;
    float x2p = 0.f;
    #pragma unroll
    for (int j = 0; j < 8; ++j) {
      int c = sc4 + j * 64;
      float4 xv = *(const float4*)(xr_s + c);
      float a0, a1, a2, a3;
      if (level) {
        float4 qv = *(const float4*)(qr_s + c);
        a0 = xv.x - qv.x; a1 = xv.y - qv.y; a2 = xv.z - qv.z; a3 = xv.w - qv.w;
      } else { a0 = xv.x; a1 = xv.y; a2 = xv.z; a3 = xv.w; }
      _Float16 h0 = (_Float16)a0, h1 = (_Float16)a1, h2 = (_Float16)a2, h3 = (_Float16)a3;
      f16x4v hv; hv[0] = h0; hv[1] = h1; hv[2] = h2; hv[3] = h3;
      f16x4v lv;
      lv[0] = (_Float16)(a0 - (float)h0);
      lv[1] = (_Float16)(a1 - (float)h1);
      lv[2] = (_Float16)(a2 - (float)h2);
      lv[3] = (_Float16)(a3 - (float)h3);
      *(f16x4v*)(&Ah[srow * APAD + c]) = hv;
      *(f16x4v*)(&Al[srow * APAD + c]) = lv;
      x2p = fmaf(a3, a3, fmaf(a2, a2, fmaf(a1, a1, fmaf(a0, a0, x2p))));
    }
    #pragma unroll
    for (int m = 1; m < 16; m <<= 1) x2p += __shfl_xor(x2p, m, 64);
    if ((tid & 15) == 0) x2s[srow] = x2p;
  }

  f32x4 acc[2][8];
  #pragma unroll
  for (int mt = 0; mt < 2; ++mt)
    #pragma unroll
    for (int nt = 0; nt < 8; ++nt) acc[mt][nt] = (f32x4){0.f, 0.f, 0.f, 0.f};

  const _Float16* bhbase = cbh + (size_t)(slab + l15) * DIM + l4 * 8;
  const _Float16* blbase = cbl + (size_t)(slab + l15) * DIM + l4 * 8;

  __syncthreads();   // staging + c2s/probs init visible; NO barriers after this until epilogue

  // ---- K-loop: register-double-buffered B, one step of lookahead
  f16x8 Bh0[8], Bl0[8], Bh1[8], Bl1[8];

  #define LOADB(BH, BL, k)                                            \
    _Pragma("unroll")                                                 \
    for (int nt = 0; nt < 8; ++nt) {                                  \
      size_t off = (size_t)nt * 16 * DIM + (k) * 32;                  \
      BH[nt] = *(const f16x8*)(bhbase + off);                         \
      BL[nt] = *(const f16x8*)(blbase + off);                         \
    }

  #define STEP(k, BH, BL)                                             \
    {                                                                 \
      f16x8 ah[2], al[2];                                             \
      _Pragma("unroll")                                               \
      for (int mt = 0; mt < 2; ++mt) {                                \
        int o = (mt * 16 + l15) * APAD + (k) * 32 + l4 * 8;           \
        ah[mt] = *(const f16x8*)(&Ah[o]);                             \
        al[mt] = *(const f16x8*)(&Al[o]);                             \
      }                                                               \
      _Pragma("unroll")                                               \
      for (int nt = 0; nt < 8; ++nt) {                                \
        _Pragma("unroll")                                             \
        for (int mt = 0; mt < 2; ++mt)                                \
          acc[mt][nt] = __builtin_amdgcn_mfma_f32_16x16x32_f16(ah[mt], BH[nt], acc[mt][nt], 0, 0, 0); \
        _Pragma("unroll")                                             \
        for (int mt = 0; mt < 2; ++mt)                                \
          acc[mt][nt] = __builtin_amdgcn_mfma_f32_16x16x32_f16(ah[mt], BL[nt], acc[mt][nt], 0, 0, 0); \
        _Pragma("unroll")                                             \
        for (int mt = 0; mt < 2; ++mt)                                \
          acc[mt][nt] = __builtin_amdgcn_mfma_f32_16x16x32_f16(al[mt], BH[nt], acc[mt][nt], 0, 0, 0); \
      }                                                               \
    }

  LOADB(Bh0, Bl0, 0)
  #pragma unroll
  for (int kk = 0; kk < 8; ++kk) {
    const int k0 = kk * 2, k1 = kk * 2 + 1;
    LOADB(Bh1, Bl1, k1)
    STEP(k0, Bh0, Bl0)
    if (k1 + 1 < 16) { LOADB(Bh0, Bl0, k1 + 1) }
    STEP(k1, Bh1, Bl1)
  }
  #undef LOADB
  #undef STEP

  __syncthreads();

  // ---- epilogue: d2, argmin (first-index ties), softmax probs
  float c2v[8];
  #pragma unroll
  for (int nt = 0; nt < 8; ++nt) c2v[nt] = c2s[slab + nt * 16 + l15];

  // pass 1: per-wave argmin over this wave's 128 codes
  #pragma unroll
  for (int mt = 0; mt < 2; ++mt) {
    #pragma unroll
    for (int r = 0; r < 4; ++r) {
      int t = mt * 16 + l4 * 4 + r;
      float x2t = x2s[t];
      float best = FLT_MAX; int bc = 0x7fffffff;
      #pragma unroll
      for (int nt = 0; nt < 8; ++nt) {
        float t1 = x2t + c2v[nt];
        float d2 = t1 - 2.0f * acc[mt][nt][r];
        acc[mt][nt][r] = d2;
        int c = slab + nt * 16 + l15;
        if (d2 < best) { best = d2; bc = c; }   // ascending c per lane -> first wins
      }
      #pragma unroll
      for (int m = 1; m < 16; m <<= 1) {
        float ob = __shfl_xor(best, m, 64);
        int oc = __shfl_xor(bc, m, 64);
        if (ob < best || (ob == best && oc < bc)) { best = ob; bc = oc; }
      }
      if (l15 == 0) { wredd[w][t] = best; wredi[w][t] = bc; }
    }
  }
  __syncthreads();

  // pass 2: combine the 8 waves' partial argmins
  float bfin[2][4];
  #pragma unroll
  for (int mt = 0; mt < 2; ++mt) {
    #pragma unroll
    for (int r = 0; r < 4; ++r) {
      int t = mt * 16 + l4 * 4 + r;
      float best = FLT_MAX; int bc = 0x7fffffff;
      #pragma unroll
      for (int wv = 0; wv < 8; ++wv) {
        float ob = wredd[wv][t]; int oc = wredi[wv][t];
        if (ob < best || (ob == best && oc < bc)) { best = ob; bc = oc; }
      }
      bfin[mt][r] = best;
      if (w == 0 && l15 == 0) {
        fcode[t] = bc;
        codes_out[(size_t)(tok0 + t) * LEVELS + level] = (float)bc;
      }
    }
  }
  __syncthreads();

  // pass 3: Z = sum exp(d2min - d2)
  #pragma unroll
  for (int mt = 0; mt < 2; ++mt) {
    #pragma unroll
    for (int r = 0; r < 4; ++r) {
      int t = mt * 16 + l4 * 4 + r;
      float z = 0.f;
      #pragma unroll
      for (int nt = 0; nt < 8; ++nt) {
        float p = __expf(bfin[mt][r] - acc[mt][nt][r]);
        acc[mt][nt][r] = p;
        z += p;
      }
      #pragma unroll
      for (int m = 1; m < 16; m <<= 1) z += __shfl_xor(z, m, 64);
      if (l15 == 0) wredz[w][t] = z;
    }
  }
  __syncthreads();

  float zin[2][4];
  #pragma unroll
  for (int mt = 0; mt < 2; ++mt) {
    #pragma unroll
    for (int r = 0; r < 4; ++r) {
      int t = mt * 16 + l4 * 4 + r;
      float Z = 0.f;
      #pragma unroll
      for (int wv = 0; wv < 8; ++wv) Z += wredz[wv][t];
      zin[mt][r] = 1.0f / Z;
    }
  }
  __syncthreads();

  // probs accumulation: each wave owns its 128-code slab (no conflicts)
  #pragma unroll
  for (int nt = 0; nt < 8; ++nt) {
    float v = 0.f;
    #pragma unroll
    for (int mt = 0; mt < 2; ++mt)
      #pragma unroll
      for (int r = 0; r < 4; ++r) v = fmaf(acc[mt][nt][r], zin[mt][r], v);
    v += __shfl_xor(v, 16, 64);
    v += __shfl_xor(v, 32, 64);
    if (l4 == 0) probs_lds[slab + nt * 16 + l15] += v;
  }
  __syncthreads();
  for (int i = tid; i < KCODES; i += 512) atomicAdd(&probs_g[i], probs_lds[i]);
  __syncthreads();

  // ---- fused update: qsum += cb[code]; commit partial
  {
    const int urow = tid >> 4;
    const int uc = (tid & 15) * 4;
    const int code = fcode[urow];
    const float* cbr = cbf + (size_t)code * DIM;
    const float* xr = x + (size_t)(tok0 + urow) * DIM;
    float* qr = qsum + (size_t)(tok0 + urow) * DIM;
    float sq = 0.f;
    #pragma unroll
    for (int j = 0; j < 8; ++j) {
      int d = uc + j * 64;
      float4 cv = *(const float4*)(cbr + d);
      float4 nv;
      if (level) {
        float4 qv = *(const float4*)(qr + d);
        nv = make_float4(qv.x + cv.x, qv.y + cv.y, qv.z + cv.z, qv.w + cv.w);
      } else nv = cv;
      *(float4*)(qr + d) = nv;
      float4 xv = *(const float4*)(xr + d);
      float a = xv.x - nv.x, b = xv.y - nv.y, c = xv.z - nv.z, e = xv.w - nv.w;
      sq = fmaf(a, a, sq); sq = fmaf(b, b, sq); sq = fmaf(c, c, sq); sq = fmaf(e, e, sq);
    }
    #pragma unroll
    for (int m = 32; m; m >>= 1) sq += __shfl_xor(sq, m, 64);
    if (l == 0) wpart[w] = sq;
    __syncthreads();
    if (tid == 0) {
      float s = 0.f;
      #pragma unroll
      for (int i = 0; i < 8; ++i) s += wpart[i];
      partials[level * NBLK_B + blockIdx.x] = s;
    }
  }
}

// ---------------------------------------------------------------- losses
__global__ void finalize_kernel(const float* __restrict__ ws, float* __restrict__ out) {
  const int tid = threadIdx.x;   // 1024 threads
  __shared__ float red[1024];
  float usum = 0.f, csum = 0.f;
  for (int lev = 0; lev < LEVELS; ++lev) {
    float a = ws[WS_PROBS + lev*KCODES + tid] * (1.0f/N_TOK);
    a = fmaxf(a, 1e-5f);
    red[tid] = a * logf(a);
    __syncthreads();
    for (int s = 512; s; s >>= 1) { if (tid < s) red[tid] += red[tid+s]; __syncthreads(); }
    if (tid == 0) usum += 6.9314718055994531f + red[0];
    __syncthreads();
    red[tid] = ws[WS_COMMIT + lev*NBLK_B + tid] + ws[WS_COMMIT + lev*NBLK_B + tid + 1024];
    __syncthreads();
    for (int s = 512; s; s >>= 1) { if (tid < s) red[tid] += red[tid+s]; __syncthreads(); }
    if (tid == 0) csum += red[0];
    __syncthreads();
  }
  if (tid == 0) {
    out[OUT_COMMIT] = (0.25f/3.0f) * (csum / (float)(N_TOK*DIM));
    out[OUT_USAGE]  = (1e-3f/3.0f) * usum;
  }
}

// ---------------------------------------------------------------- launch
extern "C" void kernel_launch(void* const* d_in, const int* in_sizes, int n_in,
                              void* d_out, int out_size, void* d_ws, size_t ws_size,
                              hipStream_t stream) {
  const float* x  = (const float*)d_in[0];
  const float* cb = (const float*)d_in[1];
  float* out = (float*)d_out;
  float* ws  = (float*)d_ws;

  // zero probs + commit-partial accumulators (c2 region harmlessly included)
  hipMemsetAsync(d_ws, 0, WS_SMALL_BYTES, stream);

  _Float16* cbh = (_Float16*)((char*)d_ws + WS_CBH_BYTES);
  _Float16* cbl = (_Float16*)((char*)d_ws + WS_CBL_BYTES);

  split_kernel<<<(LEVELS*KCODES*DIM/4)/256, 256, 0, stream>>>(cb, cbh, cbl);
  c2_kernel<<<(LEVELS*KCODES)/4, 256, 0, stream>>>(cb, ws);

  for (int level = 0; level < LEVELS; ++level) {
    rvq_fused_kernel<<<N_TOK/32, 512, 0, stream>>>(
        x, out,
        cbh + (size_t)level*KCODES*DIM, cbl + (size_t)level*KCODES*DIM,
        cb + (size_t)level*KCODES*DIM,
        ws + WS_C2 + level*KCODES, ws + WS_PROBS + level*KCODES,
        out + OUT_CODES, ws + WS_COMMIT, level);
  }
  finalize_kernel<<<1, 1024, 0, stream>>>(ws, out);
}

// Round 6
// 285.528 us; speedup vs baseline: 1.8521x; 1.0107x over previous
//
#include <hip/hip_runtime.h>
#include <cfloat>

#define N_TOK 8192
#define DIM 512
#define KCODES 1024
#define LEVELS 3

// d_out float offsets
#define OUT_CODES (N_TOK*DIM)
#define OUT_COMMIT (OUT_CODES + N_TOK*LEVELS)
#define OUT_USAGE (OUT_COMMIT + 1)

// ws float offsets (small region)
#define WS_C2 0
#define WS_PROBS 3072
#define WS_COMMIT 6144
#define NBLK_B 2048
#define WS_SMALL_BYTES 49152
// byte offsets (large region)
#define WS_CBH_BYTES 81920
#define WS_CBL_BYTES (WS_CBH_BYTES + (size_t)LEVELS*KCODES*DIM*2)

#define APAD 520   // A LDS row stride in f16

typedef _Float16 f16x8 __attribute__((ext_vector_type(8)));
typedef _Float16 f16x4v __attribute__((ext_vector_type(4)));
typedef float f32x4 __attribute__((ext_vector_type(4)));

// ---------------------------------------------------------------- c2 = ||cb_k||^2
__global__ void c2_kernel(const float* __restrict__ cb, float* __restrict__ ws) {
  int row = blockIdx.x * 4 + (threadIdx.x >> 6);   // 0..3071
  int lane = threadIdx.x & 63;
  const float* p = cb + (size_t)row * DIM;
  float s = 0.f;
  #pragma unroll
  for (int j = 0; j < DIM/64; ++j) { float v = p[lane + 64*j]; s = fmaf(v, v, s); }
  #pragma unroll
  for (int m = 32; m; m >>= 1) s += __shfl_xor(s, m, 64);
  if (lane == 0) ws[WS_C2 + row] = s;
}

// ---------------------------------------------------------------- cb f32 -> f16 hi/lo split
__global__ void split_kernel(const float* __restrict__ cb,
                             _Float16* __restrict__ ch, _Float16* __restrict__ cl) {
  size_t i = ((size_t)blockIdx.x * 256 + threadIdx.x) * 4;
  float4 v = *(const float4*)(cb + i);
  f16x4v h, lo;
  h[0] = (_Float16)v.x; h[1] = (_Float16)v.y; h[2] = (_Float16)v.z; h[3] = (_Float16)v.w;
  lo[0] = (_Float16)(v.x - (float)h[0]);
  lo[1] = (_Float16)(v.y - (float)h[1]);
  lo[2] = (_Float16)(v.z - (float)h[2]);
  lo[3] = (_Float16)(v.w - (float)h[3]);
  *(f16x4v*)(ch + i) = h;
  *(f16x4v*)(cl + i) = lo;
}

// forced-residency global load: SGPR base + 32b VGPR offset + literal imm offset
template<int IMM>
__device__ __forceinline__ uint4 gld(const _Float16* base, unsigned voff) {
  uint4 r;
  asm volatile("global_load_dwordx4 %0, %1, %2 offset:%3"
               : "=v"(r) : "v"(voff), "s"(base), "i"(IMM));
  return r;
}

#define WAITV(N) asm volatile("s_waitcnt vmcnt(" #N ")");
#define SB __builtin_amdgcn_sched_barrier(0x3F7);   // block only MFMA from crossing

// ---------------------------------------------------------------- fused level kernel
// 512 threads = 8 waves. Block = 32 tokens x 1024 codes, K=512 in 16 steps of 32.
// Wave w owns codes [w*128, w*128+128): mt=2 M-tiles x nt=8 N-tiles of 16x16x32.
// Residual hi/lo staged in LDS once (no barriers in K-loop); B hand-pipelined:
// asm global loads (forced VGPR dbuf) + counted vmcnt, one k-step of lookahead.
__launch_bounds__(512, 2)
__global__ void rvq_fused_kernel(const float* __restrict__ x,
                                 float* __restrict__ qsum,
                                 const _Float16* __restrict__ cbh,
                                 const _Float16* __restrict__ cbl,
                                 const float* __restrict__ cbf,
                                 const float* __restrict__ c2,
                                 float* __restrict__ probs_g,
                                 float* __restrict__ codes_out,
                                 float* __restrict__ partials,
                                 int level)
{
  __shared__ _Float16 Ah[32*APAD];
  __shared__ _Float16 Al[32*APAD];
  __shared__ float c2s[KCODES];
  __shared__ float probs_lds[KCODES];
  __shared__ float x2s[32];
  __shared__ float wredd[8][32];
  __shared__ int   wredi[8][32];
  __shared__ float wredz[8][32];
  __shared__ int   fcode[32];
  __shared__ float wpart[8];

  const int tid = threadIdx.x;
  const int w = tid >> 6, l = tid & 63;
  const int l15 = l & 15, l4 = l >> 4;
  const int tok0 = blockIdx.x * 32;
  const int slab = w * 128;

  for (int i = tid; i < KCODES; i += 512) { c2s[i] = c2[i]; probs_lds[i] = 0.f; }

  // ---- one-time A staging: residual hi/lo split -> LDS, fused x2
  {
    const int srow = tid >> 4;          // 0..31
    const int sc4 = (tid & 15) * 4;     // float4 col base
    const float* xr_s = x + (size_t)(tok0 + srow) * DIM;
    const float* qr_s = qsum + (size_t)(tok0 + srow) * DIM;
    float x2p = 0.f;
    #pragma unroll
    for (int j = 0; j < 8; ++j) {
      int c = sc4 + j * 64;
      float4 xv = *(const float4*)(xr_s + c);
      float a0, a1, a2, a3;
      if (level) {
        float4 qv = *(const float4*)(qr_s + c);
        a0 = xv.x - qv.x; a1 = xv.y - qv.y; a2 = xv.z - qv.z; a3 = xv.w - qv.w;
      } else { a0 = xv.x; a1 = xv.y; a2 = xv.z; a3 = xv.w; }
      _Float16 h0 = (_Float16)a0, h1 = (_Float16)a1, h2 = (_Float16)a2, h3 = (_Float16)a3;
      f16x4v hv; hv[0] = h0; hv[1] = h1; hv[2] = h2; hv[3] = h3;
      f16x4v lv;
      lv[0] = (_Float16)(a0 - (float)h0);
      lv[1] = (_Float16)(a1 - (float)h1);
      lv[2] = (_Float16)(a2 - (float)h2);
      lv[3] = (_Float16)(a3 - (float)h3);
      *(f16x4v*)(&Ah[srow * APAD + c]) = hv;
      *(f16x4v*)(&Al[srow * APAD + c]) = lv;
      x2p = fmaf(a3, a3, fmaf(a2, a2, fmaf(a1, a1, fmaf(a0, a0, x2p))));
    }
    #pragma unroll
    for (int m = 1; m < 16; m <<= 1) x2p += __shfl_xor(x2p, m, 64);
    if ((tid & 15) == 0) x2s[srow] = x2p;
  }

  f32x4 acc[2][8];
  #pragma unroll
  for (int mt = 0; mt < 2; ++mt)
    #pragma unroll
    for (int nt = 0; nt < 8; ++nt) acc[mt][nt] = (f32x4){0.f, 0.f, 0.f, 0.f};

  // per-nt byte offsets into the level codebook (same for cbh and cbl)
  unsigned boff[8];
  #pragma unroll
  for (int nt = 0; nt < 8; ++nt)
    boff[nt] = (unsigned)((((slab + nt * 16 + l15) * DIM) + l4 * 8) * 2);

  __syncthreads();   // staging + c2s init visible; NO barriers until epilogue

  // ---- K-loop: asm-pipelined B (dbuf b0/b1), counted vmcnt, depth 1
  uint4 b0[16], b1[16];

  #define ISSUE(B, KK) { \
    _Pragma("unroll") \
    for (int nt = 0; nt < 8; ++nt) { \
      B[2*nt]   = gld<(KK)*64>(cbh, boff[nt]); \
      B[2*nt+1] = gld<(KK)*64>(cbl, boff[nt]); \
    } }

  #define STEPK(KK, B) { \
    f16x8 ah[2], al[2]; \
    _Pragma("unroll") \
    for (int mt = 0; mt < 2; ++mt) { \
      int o = (mt * 16 + l15) * APAD + (KK) * 32 + l4 * 8; \
      ah[mt] = *(const f16x8*)(&Ah[o]); \
      al[mt] = *(const f16x8*)(&Al[o]); \
    } \
    _Pragma("unroll") \
    for (int nt = 0; nt < 8; ++nt) { \
      f16x8 bh = __builtin_bit_cast(f16x8, B[2*nt]); \
      f16x8 bl = __builtin_bit_cast(f16x8, B[2*nt+1]); \
      _Pragma("unroll") \
      for (int mt = 0; mt < 2; ++mt) \
        acc[mt][nt] = __builtin_amdgcn_mfma_f32_16x16x32_f16(ah[mt], bh, acc[mt][nt], 0, 0, 0); \
      _Pragma("unroll") \
      for (int mt = 0; mt < 2; ++mt) \
        acc[mt][nt] = __builtin_amdgcn_mfma_f32_16x16x32_f16(ah[mt], bl, acc[mt][nt], 0, 0, 0); \
      _Pragma("unroll") \
      for (int mt = 0; mt < 2; ++mt) \
        acc[mt][nt] = __builtin_amdgcn_mfma_f32_16x16x32_f16(al[mt], bh, acc[mt][nt], 0, 0, 0); \
    } }

  ISSUE(b0, 0)
  ISSUE(b1, 1)   WAITV(16) SB STEPK(0,  b0)
  ISSUE(b0, 2)   WAITV(16) SB STEPK(1,  b1)
  ISSUE(b1, 3)   WAITV(16) SB STEPK(2,  b0)
  ISSUE(b0, 4)   WAITV(16) SB STEPK(3,  b1)
  ISSUE(b1, 5)   WAITV(16) SB STEPK(4,  b0)
  ISSUE(b0, 6)   WAITV(16) SB STEPK(5,  b1)
  ISSUE(b1, 7)   WAITV(16) SB STEPK(6,  b0)
  ISSUE(b0, 8)   WAITV(16) SB STEPK(7,  b1)
  ISSUE(b1, 9)   WAITV(16) SB STEPK(8,  b0)
  ISSUE(b0, 10)  WAITV(16) SB STEPK(9,  b1)
  ISSUE(b1, 11)  WAITV(16) SB STEPK(10, b0)
  ISSUE(b0, 12)  WAITV(16) SB STEPK(11, b1)
  ISSUE(b1, 13)  WAITV(16) SB STEPK(12, b0)
  ISSUE(b0, 14)  WAITV(16) SB STEPK(13, b1)
  ISSUE(b1, 15)  WAITV(16) SB STEPK(14, b0)
                 WAITV(0)  SB STEPK(15, b1)
  #undef ISSUE
  #undef STEPK

  __syncthreads();

  // ---- epilogue: d2, argmin (first-index ties), softmax probs
  float c2v[8];
  #pragma unroll
  for (int nt = 0; nt < 8; ++nt) c2v[nt] = c2s[slab + nt * 16 + l15];

  // pass 1: per-wave argmin over this wave's 128 codes
  #pragma unroll
  for (int mt = 0; mt < 2; ++mt) {
    #pragma unroll
    for (int r = 0; r < 4; ++r) {
      int t = mt * 16 + l4 * 4 + r;
      float x2t = x2s[t];
      float best = FLT_MAX; int bc = 0x7fffffff;
      #pragma unroll
      for (int nt = 0; nt < 8; ++nt) {
        float t1 = x2t + c2v[nt];
        float d2 = t1 - 2.0f * acc[mt][nt][r];
        acc[mt][nt][r] = d2;
        int c = slab + nt * 16 + l15;
        if (d2 < best) { best = d2; bc = c; }   // ascending c per lane -> first wins
      }
      #pragma unroll
      for (int m = 1; m < 16; m <<= 1) {
        float ob = __shfl_xor(best, m, 64);
        int oc = __shfl_xor(bc, m, 64);
        if (ob < best || (ob == best && oc < bc)) { best = ob; bc = oc; }
      }
      if (l15 == 0) { wredd[w][t] = best; wredi[w][t] = bc; }
    }
  }
  __syncthreads();

  // pass 2: combine the 8 waves' partial argmins
  float bfin[2][4];
  #pragma unroll
  for (int mt = 0; mt < 2; ++mt) {
    #pragma unroll
    for (int r = 0; r < 4; ++r) {
      int t = mt * 16 + l4 * 4 + r;
      float best = FLT_MAX; int bc = 0x7fffffff;
      #pragma unroll
      for (int wv = 0; wv < 8; ++wv) {
        float ob = wredd[wv][t]; int oc = wredi[wv][t];
        if (ob < best || (ob == best && oc < bc)) { best = ob; bc = oc; }
      }
      bfin[mt][r] = best;
      if (w == 0 && l15 == 0) {
        fcode[t] = bc;
        codes_out[(size_t)(tok0 + t) * LEVELS + level] = (float)bc;
      }
    }
  }
  __syncthreads();

  // pass 3: Z = sum exp(d2min - d2)
  #pragma unroll
  for (int mt = 0; mt < 2; ++mt) {
    #pragma unroll
    for (int r = 0; r < 4; ++r) {
      int t = mt * 16 + l4 * 4 + r;
      float z = 0.f;
      #pragma unroll
      for (int nt = 0; nt < 8; ++nt) {
        float p = __expf(bfin[mt][r] - acc[mt][nt][r]);
        acc[mt][nt][r] = p;
        z += p;
      }
      #pragma unroll
      for (int m = 1; m < 16; m <<= 1) z += __shfl_xor(z, m, 64);
      if (l15 == 0) wredz[w][t] = z;
    }
  }
  __syncthreads();

  float zin[2][4];
  #pragma unroll
  for (int mt = 0; mt < 2; ++mt) {
    #pragma unroll
    for (int r = 0; r < 4; ++r) {
      int t = mt * 16 + l4 * 4 + r;
      float Z = 0.f;
      #pragma unroll
      for (int wv = 0; wv < 8; ++wv) Z += wredz[wv][t];
      zin[mt][r] = 1.0f / Z;
    }
  }
  __syncthreads();

  // probs accumulation: each wave owns its 128-code slab (no conflicts)
  #pragma unroll
  for (int nt = 0; nt < 8; ++nt) {
    float v = 0.f;
    #pragma unroll
    for (int mt = 0; mt < 2; ++mt)
      #pragma unroll
      for (int r = 0; r < 4; ++r) v = fmaf(acc[mt][nt][r], zin[mt][r], v);
    v += __shfl_xor(v, 16, 64);
    v += __shfl_xor(v, 32, 64);
    if (l4 == 0) probs_lds[slab + nt * 16 + l15] += v;
  }
  __syncthreads();
  for (int i = tid; i < KCODES; i += 512) atomicAdd(&probs_g[i], probs_lds[i]);
  __syncthreads();

  // ---- fused update: qsum += cb[code]; commit partial
  {
    const int urow = tid >> 4;
    const int uc = (tid & 15) * 4;
    const int code = fcode[urow];
    const float* cbr = cbf + (size_t)code * DIM;
    const float* xr = x + (size_t)(tok0 + urow) * DIM;
    float* qr = qsum + (size_t)(tok0 + urow) * DIM;
    float sq = 0.f;
    #pragma unroll
    for (int j = 0; j < 8; ++j) {
      int d = uc + j * 64;
      float4 cv = *(const float4*)(cbr + d);
      float4 nv;
      if (level) {
        float4 qv = *(const float4*)(qr + d);
        nv = make_float4(qv.x + cv.x, qv.y + cv.y, qv.z + cv.z, qv.w + cv.w);
      } else nv = cv;
      *(float4*)(qr + d) = nv;
      float4 xv = *(const float4*)(xr + d);
      float a = xv.x - nv.x, b = xv.y - nv.y, c = xv.z - nv.z, e = xv.w - nv.w;
      sq = fmaf(a, a, sq); sq = fmaf(b, b, sq); sq = fmaf(c, c, sq); sq = fmaf(e, e, sq);
    }
    #pragma unroll
    for (int m = 32; m; m >>= 1) sq += __shfl_xor(sq, m, 64);
    if (l == 0) wpart[w] = sq;
    __syncthreads();
    if (tid == 0) {
      float s = 0.f;
      #pragma unroll
      for (int i = 0; i < 8; ++i) s += wpart[i];
      partials[level * NBLK_B + blockIdx.x] = s;
    }
  }
}

// ---------------------------------------------------------------- losses
__global__ void finalize_kernel(const float* __restrict__ ws, float* __restrict__ out) {
  const int tid = threadIdx.x;   // 1024 threads
  __shared__ float red[1024];
  float usum = 0.f, csum = 0.f;
  for (int lev = 0; lev < LEVELS; ++lev) {
    float a = ws[WS_PROBS + lev*KCODES + tid] * (1.0f/N_TOK);
    a = fmaxf(a, 1e-5f);
    red[tid] = a * logf(a);
    __syncthreads();
    for (int s = 512; s; s >>= 1) { if (tid < s) red[tid] += red[tid+s]; __syncthreads(); }
    if (tid == 0) usum += 6.9314718055994531f + red[0];
    __syncthreads();
    red[tid] = ws[WS_COMMIT + lev*NBLK_B + tid] + ws[WS_COMMIT + lev*NBLK_B + tid + 1024];
    __syncthreads();
    for (int s = 512; s; s >>= 1) { if (tid < s) red[tid] += red[tid+s]; __syncthreads(); }
    if (tid == 0) csum += red[0];
    __syncthreads();
  }
  if (tid == 0) {
    out[OUT_COMMIT] = (0.25f/3.0f) * (csum / (float)(N_TOK*DIM));
    out[OUT_USAGE]  = (1e-3f/3.0f) * usum;
  }
}

// ---------------------------------------------------------------- launch
extern "C" void kernel_launch(void* const* d_in, const int* in_sizes, int n_in,
                              void* d_out, int out_size, void* d_ws, size_t ws_size,
                              hipStream_t stream) {
  const float* x  = (const float*)d_in[0];
  const float* cb = (const float*)d_in[1];
  float* out = (float*)d_out;
  float* ws  = (float*)d_ws;

  // zero probs + commit-partial accumulators (c2 region harmlessly included)
  hipMemsetAsync(d_ws, 0, WS_SMALL_BYTES, stream);

  _Float16* cbh = (_Float16*)((char*)d_ws + WS_CBH_BYTES);
  _Float16* cbl = (_Float16*)((char*)d_ws + WS_CBL_BYTES);

  split_kernel<<<(LEVELS*KCODES*DIM/4)/256, 256, 0, stream>>>(cb, cbh, cbl);
  c2_kernel<<<(LEVELS*KCODES)/4, 256, 0, stream>>>(cb, ws);

  for (int level = 0; level < LEVELS; ++level) {
    rvq_fused_kernel<<<N_TOK/32, 512, 0, stream>>>(
        x, out,
        cbh + (size_t)level*KCODES*DIM, cbl + (size_t)level*KCODES*DIM,
        cb + (size_t)level*KCODES*DIM,
        ws + WS_C2 + level*KCODES, ws + WS_PROBS + level*KCODES,
        out + OUT_CODES, ws + WS_COMMIT, level);
  }
  finalize_kernel<<<1, 1024, 0, stream>>>(ws, out);
}